// Round 1
// baseline (515.039 us; speedup 1.0000x reference)
//
#include <hip/hip_runtime.h>
#include <math.h>

#define BB 2
#define HH 8
#define SS 2048
#define CC 64
#define CIN 512
#define DDIM 512           // H*C
#define MM (BB*SS)         // 4096
#define KSPLIT 4
#define KDOM (SS / KSPLIT) // 512 keys per split block
#define NCHUNK (KDOM / 64) // 8

#define LOG2E 1.4426950408889634f
#define SHIFT2 (16.0f * LOG2E)   // softmax shift in log2 domain

using short8  = __attribute__((ext_vector_type(8))) short;
using float4v = __attribute__((ext_vector_type(4))) float;

__device__ __forceinline__ unsigned short tob(float f) {
    unsigned u = __float_as_uint(f);
    unsigned r = (u + 0x7fffu + ((u >> 16) & 1u)) >> 16;
    return (unsigned short)r;
}
__device__ __forceinline__ float fromb(unsigned short u) {
    return __uint_as_float(((unsigned)u) << 16);
}

// ---------------------------------------------------------------- convert ---
__global__ __launch_bounds__(256) void convert_all(
    const float* __restrict__ x,
    const float* __restrict__ wq, const float* __restrict__ wk,
    const float* __restrict__ wv, const float* __restrict__ wg,
    const float* __restrict__ wo,
    unsigned short* __restrict__ xb,
    unsigned short* __restrict__ wqb, unsigned short* __restrict__ wkb,
    unsigned short* __restrict__ wvb, unsigned short* __restrict__ wgb,
    unsigned short* __restrict__ wob)
{
    const int NX4 = MM * CIN / 4;       // 524288
    int i = blockIdx.x * blockDim.x + threadIdx.x;
    const float* src; unsigned short* dst; float scale = 1.0f; int off;
    if (i < NX4) { src = x; dst = xb; off = i; }
    else {
        int j = i - NX4;
        int seg = j >> 16;              // 65536 float4 per 512x512 weight
        off = j & 65535;
        // Wq pre-scaled by (1/8)*log2(e) so QK^T scores land in log2 units.
        if      (seg == 0) { src = wq; dst = wqb; scale = 0.125f * LOG2E; }
        else if (seg == 1) { src = wk; dst = wkb; }
        else if (seg == 2) { src = wv; dst = wvb; }
        else if (seg == 3) { src = wg; dst = wgb; }
        else               { src = wo; dst = wob; }
    }
    float4 v = ((const float4*)src)[off];
    ushort4 o;
    o.x = tob(v.x * scale); o.y = tob(v.y * scale);
    o.z = tob(v.z * scale); o.w = tob(v.w * scale);
    ((ushort4*)dst)[off] = o;
}

// ------------------------------------------------------------- projection ---
// mode (blockIdx.z): 0 Q->[B,H,S,C] (pre-scaled, log2-domain), 1 K->[B,H,S,C],
// 2 V->[B,H,C,S] (LDS transpose), 3 G=sigmoid(P+bg)->[MM][512]
__global__ __launch_bounds__(256) void proj_gemm(
    const unsigned short* __restrict__ X,
    const unsigned short* __restrict__ Wq,
    const unsigned short* __restrict__ Wk,
    const unsigned short* __restrict__ Wv,
    const unsigned short* __restrict__ Wg,
    const float* __restrict__ bg,
    unsigned short* __restrict__ Qd,
    unsigned short* __restrict__ Kd,
    unsigned short* __restrict__ Vd,
    unsigned short* __restrict__ Gd)
{
    __shared__ __align__(16) unsigned short At[64][72];
    __shared__ __align__(16) unsigned short Bt[64][72];

    int mode = blockIdx.z;
    const unsigned short* W = (mode == 0) ? Wq : (mode == 1) ? Wk : (mode == 2) ? Wv : Wg;

    int m0 = blockIdx.y * 64;
    int n0 = blockIdx.x * 64;
    int tid = threadIdx.x;
    int w = tid >> 6, lane = tid & 63;
    int quad = lane >> 4, l16 = lane & 15;
    int wm = w & 1, wn = w >> 1;

    float4v acc[2][2];
    for (int a = 0; a < 2; ++a) for (int c = 0; c < 2; ++c) acc[a][c] = (float4v)0.0f;

    for (int kc = 0; kc < CIN; kc += 64) {
        for (int it = 0; it < 2; ++it) {
            int idx = it * 2048 + tid * 8;
            int row = idx >> 6, col = idx & 63;
            *(short8*)&At[row][col] = *(const short8*)&X[(size_t)(m0 + row) * CIN + kc + col];
            *(short8*)&Bt[row][col] = *(const short8*)&W[(size_t)(n0 + row) * CIN + kc + col];
        }
        __syncthreads();
        for (int ks = 0; ks < 2; ++ks) {
            short8 a0 = *(const short8*)&At[wm * 32 + l16][ks * 32 + quad * 8];
            short8 a1 = *(const short8*)&At[wm * 32 + 16 + l16][ks * 32 + quad * 8];
            short8 b0 = *(const short8*)&Bt[wn * 32 + l16][ks * 32 + quad * 8];
            short8 b1 = *(const short8*)&Bt[wn * 32 + 16 + l16][ks * 32 + quad * 8];
            acc[0][0] = __builtin_amdgcn_mfma_f32_16x16x32_bf16(a0, b0, acc[0][0], 0, 0, 0);
            acc[0][1] = __builtin_amdgcn_mfma_f32_16x16x32_bf16(a0, b1, acc[0][1], 0, 0, 0);
            acc[1][0] = __builtin_amdgcn_mfma_f32_16x16x32_bf16(a1, b0, acc[1][0], 0, 0, 0);
            acc[1][1] = __builtin_amdgcn_mfma_f32_16x16x32_bf16(a1, b1, acc[1][1], 0, 0, 0);
        }
        __syncthreads();
    }

    if (mode == 2) {
        for (int a = 0; a < 2; ++a) for (int c = 0; c < 2; ++c)
            for (int r = 0; r < 4; ++r) {
                int ml = wm * 32 + a * 16 + quad * 4 + r;     // s-local
                int nl = wn * 32 + c * 16 + l16;              // c-local
                At[nl][ml] = tob(acc[a][c][r]);
            }
        __syncthreads();
        int bi = m0 >> 11, h = n0 >> 6, s0 = m0 & 2047;
        int crow = tid >> 2, seg = tid & 3;
        unsigned short* dp = Vd + (((size_t)(bi * HH + h) * CC) + crow) * SS + s0 + seg * 16;
        *(short8*)dp       = *(const short8*)&At[crow][seg * 16];
        *(short8*)(dp + 8) = *(const short8*)&At[crow][seg * 16 + 8];
        return;
    }

    for (int a = 0; a < 2; ++a) for (int c = 0; c < 2; ++c)
        for (int r = 0; r < 4; ++r) {
            int gm = m0 + wm * 32 + a * 16 + quad * 4 + r;
            int gn = n0 + wn * 32 + c * 16 + l16;
            float v = acc[a][c][r];
            if (mode <= 1) {
                int bi = gm >> 11, s = gm & 2047, h = gn >> 6, cc = gn & 63;
                unsigned short* d = (mode == 0) ? Qd : Kd;
                d[(((size_t)(bi * HH + h) * SS) + s) * CC + cc] = tob(v);
            } else {
                float g = 1.0f / (1.0f + __expf(-(v + bg[gn])));
                Gd[(size_t)gm * DDIM + gn] = tob(g);
            }
        }
}

// -------------------------------------------------------------- attention ---
// Split-K flash attention, fixed-shift softmax (linear in k-chunks, log2 domain):
//   partial[split] = sum_k 2^(s2+b2) v ; lsum[split] = sum_k 2^(s2+b2)
// where s2 = (q k)/sqrt(C) * log2e (folded into Wq scale) and
// b2 = bias*log2e - 16*log2e (folded into the bias prefetch FMA).
// Block = 64 q rows (4 waves x 16), kdomain = 512 keys (8 chunks),
// grid (32, 16, 4) = 2048 blocks -> 5 resident blocks/CU (LDS-limited).
// Pipeline: K/V prefetched 1 chunk ahead; bias (cold HBM, zero reuse)
// prefetched 2 chunks ahead through 3 rotating register buffers.
__global__ __launch_bounds__(256) void attn_kernel(
    const unsigned short* __restrict__ Q,
    const unsigned short* __restrict__ K,
    const unsigned short* __restrict__ V,
    const float* __restrict__ bias,
    float* __restrict__ part,      // [KSPLIT][MM][DDIM] fp32
    float* __restrict__ Ls)        // [KSPLIT][MM][HH]   fp32
{
    __shared__ __align__(16) unsigned short Kt[64][72];   // [key][c]
    __shared__ __align__(16) unsigned short Vt[64][72];   // [c][key]
    __shared__ __align__(16) unsigned short Pt[4][16][72];// per-wave P scratch

    int qb = blockIdx.x * 64;
    int bh = blockIdx.y;               // b*H + h
    int split = blockIdx.z;
    int ksbase = split * KDOM;
    int b = bh >> 3, h = bh & 7;
    int tid = threadIdx.x;
    int w = tid >> 6, lane = tid & 63;
    int quad = lane >> 4, l16 = lane & 15;

    const unsigned short* Qbh = Q + (size_t)bh * SS * CC;
    const unsigned short* Kbh = K + (size_t)bh * SS * CC + (size_t)ksbase * CC;
    const unsigned short* Vbh = V + (size_t)bh * CC * SS + ksbase;
    // bias row base for this thread's r=0 row; r advances by SS floats.
    const float* brow0 = bias + (size_t)bh * SS * SS
                       + (size_t)(qb + w * 16 + quad * 4) * SS + ksbase + l16;

    int qrow = qb + w * 16 + l16;
    short8 aq0 = *(const short8*)&Qbh[(size_t)qrow * CC + quad * 8];
    short8 aq1 = *(const short8*)&Qbh[(size_t)qrow * CC + 32 + quad * 8];

    float lsum[4] = {0.f, 0.f, 0.f, 0.f};
    float4v accO[4];
    for (int jn = 0; jn < 4; ++jn) accO[jn] = (float4v)0.0f;

    // staging address components (per thread, two 16B pieces each for K and V)
    int srow0 = (tid * 8) >> 6,        scol0 = (tid * 8) & 63;
    int srow1 = (2048 + tid * 8) >> 6, scol1 = (2048 + tid * 8) & 63;

    // ---- prologue: K/V chunk 0; bias chunks 0 and 1 (depth-2)
    short8 pk[2][2], pv[2][2];
    float  bb[3][4][4];
    pk[0][0] = *(const short8*)&Kbh[(size_t)srow0 * CC + scol0];
    pk[0][1] = *(const short8*)&Kbh[(size_t)srow1 * CC + scol1];
    pv[0][0] = *(const short8*)&Vbh[(size_t)srow0 * SS + scol0];
    pv[0][1] = *(const short8*)&Vbh[(size_t)srow1 * SS + scol1];
#pragma unroll
    for (int j = 0; j < 4; ++j)
#pragma unroll
        for (int r = 0; r < 4; ++r)
            bb[0][j][r] = fmaf(brow0[r * SS + j * 16], LOG2E, -SHIFT2);
#pragma unroll
    for (int j = 0; j < 4; ++j)
#pragma unroll
        for (int r = 0; r < 4; ++r)
            bb[1][j][r] = fmaf(brow0[r * SS + 64 + j * 16], LOG2E, -SHIFT2);

#pragma unroll
    for (int c = 0; c < NCHUNK; ++c) {
        __syncthreads();   // previous chunk's Kt/Vt fully consumed
        *(short8*)&Kt[srow0][scol0] = pk[c & 1][0];
        *(short8*)&Kt[srow1][scol1] = pk[c & 1][1];
        *(short8*)&Vt[srow0][scol0] = pv[c & 1][0];
        *(short8*)&Vt[srow1][scol1] = pv[c & 1][1];

        // issue next chunk's K/V loads (latency hidden behind this chunk)
        if (c + 1 < NCHUNK) {
            int kbn = (c + 1) * 64;
            pk[(c + 1) & 1][0] = *(const short8*)&Kbh[(size_t)(kbn + srow0) * CC + scol0];
            pk[(c + 1) & 1][1] = *(const short8*)&Kbh[(size_t)(kbn + srow1) * CC + scol1];
            pv[(c + 1) & 1][0] = *(const short8*)&Vbh[(size_t)srow0 * SS + kbn + scol0];
            pv[(c + 1) & 1][1] = *(const short8*)&Vbh[(size_t)srow1 * SS + kbn + scol1];
        }
        // issue bias two chunks ahead (cold HBM, ~900cy: 2 chunk periods cover)
        if (c + 2 < NCHUNK) {
            int kbb = (c + 2) * 64;
#pragma unroll
            for (int j = 0; j < 4; ++j)
#pragma unroll
                for (int r = 0; r < 4; ++r)
                    bb[(c + 2) % 3][j][r] = fmaf(brow0[r * SS + kbb + j * 16], LOG2E, -SHIFT2);
        }

        __syncthreads();

        float4v sa[4];
#pragma unroll
        for (int j = 0; j < 4; ++j) sa[j] = (float4v)0.0f;
#pragma unroll
        for (int j = 0; j < 4; ++j) {
            short8 bk0 = *(const short8*)&Kt[j * 16 + l16][quad * 8];
            short8 bk1 = *(const short8*)&Kt[j * 16 + l16][32 + quad * 8];
            sa[j] = __builtin_amdgcn_mfma_f32_16x16x32_bf16(aq0, bk0, sa[j], 0, 0, 0);
            sa[j] = __builtin_amdgcn_mfma_f32_16x16x32_bf16(aq1, bk1, sa[j], 0, 0, 0);
        }

#pragma unroll
        for (int j = 0; j < 4; ++j)
#pragma unroll
            for (int r = 0; r < 4; ++r) {
                float p = __builtin_amdgcn_exp2f(sa[j][r] + bb[c % 3][j][r]);
                lsum[r] += p;
                Pt[w][quad * 4 + r][j * 16 + l16] = tob(p);
            }

#pragma unroll
        for (int ks = 0; ks < 2; ++ks) {
            short8 ap = *(const short8*)&Pt[w][l16][ks * 32 + quad * 8];
#pragma unroll
            for (int jn = 0; jn < 4; ++jn) {
                short8 bv = *(const short8*)&Vt[jn * 16 + l16][ks * 32 + quad * 8];
                accO[jn] = __builtin_amdgcn_mfma_f32_16x16x32_bf16(ap, bv, accO[jn], 0, 0, 0);
            }
        }
    }

    // row-sum reduce across 16 l16 lanes
    for (int r = 0; r < 4; ++r) {
        float s = lsum[r];
        s += __shfl_xor(s, 1, 64);
        s += __shfl_xor(s, 2, 64);
        s += __shfl_xor(s, 4, 64);
        s += __shfl_xor(s, 8, 64);
        lsum[r] = s;
    }

    // epilogue: raw partials (division + gating deferred to combine kernel)
    int mrow = b * SS + qb + w * 16 + quad * 4;          // +r
    float* pOut = part + (size_t)split * MM * DDIM;
    for (int jn = 0; jn < 4; ++jn)
        for (int r = 0; r < 4; ++r)
            pOut[(size_t)(mrow + r) * DDIM + h * 64 + jn * 16 + l16] = accO[jn][r];
    if (l16 == 0)
        for (int r = 0; r < 4; ++r)
            Ls[((size_t)split * MM + mrow + r) * HH + h] = lsum[r];
}

// ----------------------------------------------------------------- combine --
// Og = (sum_s part_s) / (sum_s Ls_s) * G  -> bf16 [MM][DDIM]
__global__ __launch_bounds__(256) void combine_kernel(
    const float* __restrict__ part,
    const float* __restrict__ Ls,
    const unsigned short* __restrict__ G,
    unsigned short* __restrict__ Og)
{
    int i = blockIdx.x * 256 + threadIdx.x;   // 0 .. MM*DDIM/4-1
    int row = i >> 7;
    int c4  = (i & 127) << 2;
    int h   = c4 >> 6;
    float l = 0.f;
#pragma unroll
    for (int s = 0; s < KSPLIT; ++s)
        l += Ls[((size_t)s * MM + row) * HH + h];
    float rl = 1.0f / l;
    float ax = 0.f, ay = 0.f, az = 0.f, aw = 0.f;
#pragma unroll
    for (int s = 0; s < KSPLIT; ++s) {
        float4 t = *(const float4*)(part + (size_t)s * MM * DDIM + (size_t)row * DDIM + c4);
        ax += t.x; ay += t.y; az += t.z; aw += t.w;
    }
    ushort4 g = *(const ushort4*)&G[(size_t)row * DDIM + c4];
    ushort4 o;
    o.x = tob(ax * rl * fromb(g.x));
    o.y = tob(ay * rl * fromb(g.y));
    o.z = tob(az * rl * fromb(g.z));
    o.w = tob(aw * rl * fromb(g.w));
    *(ushort4*)&Og[(size_t)row * DDIM + c4] = o;
}

// ---------------------------------------------------------- output GEMM -----
__global__ __launch_bounds__(256) void out_gemm(
    const unsigned short* __restrict__ Og,
    const unsigned short* __restrict__ W,
    const float* __restrict__ bo,
    float* __restrict__ out)
{
    __shared__ __align__(16) unsigned short At[64][72];
    __shared__ __align__(16) unsigned short Bt[64][72];

    int m0 = blockIdx.y * 64;
    int n0 = blockIdx.x * 64;
    int tid = threadIdx.x;
    int w = tid >> 6, lane = tid & 63;
    int quad = lane >> 4, l16 = lane & 15;
    int wm = w & 1, wn = w >> 1;

    float4v acc[2][2];
    for (int a = 0; a < 2; ++a) for (int c = 0; c < 2; ++c) acc[a][c] = (float4v)0.0f;

    for (int kc = 0; kc < DDIM; kc += 64) {
        for (int it = 0; it < 2; ++it) {
            int idx = it * 2048 + tid * 8;
            int row = idx >> 6, col = idx & 63;
            *(short8*)&At[row][col] = *(const short8*)&Og[(size_t)(m0 + row) * DDIM + kc + col];
            *(short8*)&Bt[row][col] = *(const short8*)&W[(size_t)(n0 + row) * DDIM + kc + col];
        }
        __syncthreads();
        for (int ks = 0; ks < 2; ++ks) {
            short8 a0 = *(const short8*)&At[wm * 32 + l16][ks * 32 + quad * 8];
            short8 a1 = *(const short8*)&At[wm * 32 + 16 + l16][ks * 32 + quad * 8];
            short8 b0 = *(const short8*)&Bt[wn * 32 + l16][ks * 32 + quad * 8];
            short8 b1 = *(const short8*)&Bt[wn * 32 + 16 + l16][ks * 32 + quad * 8];
            acc[0][0] = __builtin_amdgcn_mfma_f32_16x16x32_bf16(a0, b0, acc[0][0], 0, 0, 0);
            acc[0][1] = __builtin_amdgcn_mfma_f32_16x16x32_bf16(a0, b1, acc[0][1], 0, 0, 0);
            acc[1][0] = __builtin_amdgcn_mfma_f32_16x16x32_bf16(a1, b0, acc[1][0], 0, 0, 0);
            acc[1][1] = __builtin_amdgcn_mfma_f32_16x16x32_bf16(a1, b1, acc[1][1], 0, 0, 0);
        }
        __syncthreads();
    }

    for (int a = 0; a < 2; ++a) for (int c = 0; c < 2; ++c)
        for (int r = 0; r < 4; ++r) {
            int gm = m0 + wm * 32 + a * 16 + quad * 4 + r;
            int gn = n0 + wn * 32 + c * 16 + l16;
            out[(size_t)gm * DDIM + gn] = acc[a][c][r] + bo[gn];
        }
}

// ------------------------------------------------------------------ launch --
extern "C" void kernel_launch(void* const* d_in, const int* in_sizes, int n_in,
                              void* d_out, int out_size, void* d_ws, size_t ws_size,
                              hipStream_t stream)
{
    const float* x    = (const float*)d_in[0];
    const float* bias = (const float*)d_in[1];
    const float* Wq   = (const float*)d_in[2];
    const float* Wk   = (const float*)d_in[3];
    const float* Wv   = (const float*)d_in[4];
    const float* Wo   = (const float*)d_in[5];
    const float* bo   = (const float*)d_in[6];
    const float* Wg   = (const float*)d_in[7];
    const float* bg   = (const float*)d_in[8];
    float* out = (float*)d_out;

    char* ws = (char*)d_ws;
    auto alloc = [&](size_t bytes) { char* p = ws; ws += (bytes + 255) & ~(size_t)255; return p; };
    unsigned short* xb  = (unsigned short*)alloc((size_t)MM * CIN * 2);
    unsigned short* wqb = (unsigned short*)alloc((size_t)DDIM * CIN * 2);
    unsigned short* wkb = (unsigned short*)alloc((size_t)DDIM * CIN * 2);
    unsigned short* wvb = (unsigned short*)alloc((size_t)DDIM * CIN * 2);
    unsigned short* wgb = (unsigned short*)alloc((size_t)DDIM * CIN * 2);
    unsigned short* wob = (unsigned short*)alloc((size_t)DDIM * CIN * 2);
    unsigned short* Qh  = (unsigned short*)alloc((size_t)BB * HH * SS * CC * 2);
    unsigned short* Kh  = (unsigned short*)alloc((size_t)BB * HH * SS * CC * 2);
    unsigned short* Vh  = (unsigned short*)alloc((size_t)BB * HH * SS * CC * 2);
    unsigned short* Gt  = (unsigned short*)alloc((size_t)MM * DDIM * 2);
    unsigned short* Om  = (unsigned short*)alloc((size_t)MM * DDIM * 2);
    float* part = (float*)alloc((size_t)KSPLIT * MM * DDIM * 4);   // 33.6 MB
    float* Lsum = (float*)alloc((size_t)KSPLIT * MM * HH * 4);     // 512 KB

    convert_all<<<3328, 256, 0, stream>>>(x, Wq, Wk, Wv, Wg, Wo,
                                          xb, wqb, wkb, wvb, wgb, wob);
    proj_gemm<<<dim3(DDIM / 64, MM / 64, 4), 256, 0, stream>>>(
        xb, wqb, wkb, wvb, wgb, bg, Qh, Kh, Vh, Gt);
    attn_kernel<<<dim3(SS / 64, BB * HH, KSPLIT), 256, 0, stream>>>(
        Qh, Kh, Vh, bias, part, Lsum);
    combine_kernel<<<(MM * DDIM / 4) / 256, 256, 0, stream>>>(part, Lsum, Gt, Om);
    out_gemm<<<dim3(DDIM / 64, MM / 64), 256, 0, stream>>>(Om, wob, bo, out);
}

// Round 2
// 434.462 us; speedup vs baseline: 1.1855x; 1.1855x over previous
//
#include <hip/hip_runtime.h>
#include <math.h>

#define BB 2
#define HH 8
#define SS 2048
#define CC 64
#define CIN 512
#define DDIM 512           // H*C
#define MM (BB*SS)         // 4096
#define KSPLIT 2
#define KDOM (SS / KSPLIT) // 1024 keys per split block
#define NCHUNK (KDOM / 64) // 16

#define LOG2E 1.4426950408889634f
#define SHIFT2 (16.0f * LOG2E)   // softmax shift in log2 domain

using short8  = __attribute__((ext_vector_type(8))) short;
using float4v = __attribute__((ext_vector_type(4))) float;

__device__ __forceinline__ unsigned short tob(float f) {
    unsigned u = __float_as_uint(f);
    unsigned r = (u + 0x7fffu + ((u >> 16) & 1u)) >> 16;
    return (unsigned short)r;
}
__device__ __forceinline__ float fromb(unsigned short u) {
    return __uint_as_float(((unsigned)u) << 16);
}

// ---------------------------------------------------------------- convert ---
__global__ __launch_bounds__(256) void convert_all(
    const float* __restrict__ x,
    const float* __restrict__ wq, const float* __restrict__ wk,
    const float* __restrict__ wv, const float* __restrict__ wg,
    const float* __restrict__ wo,
    unsigned short* __restrict__ xb,
    unsigned short* __restrict__ wqb, unsigned short* __restrict__ wkb,
    unsigned short* __restrict__ wvb, unsigned short* __restrict__ wgb,
    unsigned short* __restrict__ wob)
{
    const int NX4 = MM * CIN / 4;       // 524288
    int i = blockIdx.x * blockDim.x + threadIdx.x;
    const float* src; unsigned short* dst; float scale = 1.0f; int off;
    if (i < NX4) { src = x; dst = xb; off = i; }
    else {
        int j = i - NX4;
        int seg = j >> 16;              // 65536 float4 per 512x512 weight
        off = j & 65535;
        // Wq pre-scaled by (1/8)*log2(e) so QK^T scores land in log2 units.
        if      (seg == 0) { src = wq; dst = wqb; scale = 0.125f * LOG2E; }
        else if (seg == 1) { src = wk; dst = wkb; }
        else if (seg == 2) { src = wv; dst = wvb; }
        else if (seg == 3) { src = wg; dst = wgb; }
        else               { src = wo; dst = wob; }
    }
    float4 v = ((const float4*)src)[off];
    ushort4 o;
    o.x = tob(v.x * scale); o.y = tob(v.y * scale);
    o.z = tob(v.z * scale); o.w = tob(v.w * scale);
    ((ushort4*)dst)[off] = o;
}

// ------------------------------------------------------------- projection ---
// mode (blockIdx.z): 0 Q->[B,H,S,C] (pre-scaled, log2-domain), 1 K->[B,H,S,C],
// 2 V->[B,H,C,S] (LDS transpose), 3 G=sigmoid(P+bg)->[MM][512]
__global__ __launch_bounds__(256) void proj_gemm(
    const unsigned short* __restrict__ X,
    const unsigned short* __restrict__ Wq,
    const unsigned short* __restrict__ Wk,
    const unsigned short* __restrict__ Wv,
    const unsigned short* __restrict__ Wg,
    const float* __restrict__ bg,
    unsigned short* __restrict__ Qd,
    unsigned short* __restrict__ Kd,
    unsigned short* __restrict__ Vd,
    unsigned short* __restrict__ Gd)
{
    __shared__ __align__(16) unsigned short At[64][72];
    __shared__ __align__(16) unsigned short Bt[64][72];

    int mode = blockIdx.z;
    const unsigned short* W = (mode == 0) ? Wq : (mode == 1) ? Wk : (mode == 2) ? Wv : Wg;

    int m0 = blockIdx.y * 64;
    int n0 = blockIdx.x * 64;
    int tid = threadIdx.x;
    int w = tid >> 6, lane = tid & 63;
    int quad = lane >> 4, l16 = lane & 15;
    int wm = w & 1, wn = w >> 1;

    float4v acc[2][2];
    for (int a = 0; a < 2; ++a) for (int c = 0; c < 2; ++c) acc[a][c] = (float4v)0.0f;

    for (int kc = 0; kc < CIN; kc += 64) {
        for (int it = 0; it < 2; ++it) {
            int idx = it * 2048 + tid * 8;
            int row = idx >> 6, col = idx & 63;
            *(short8*)&At[row][col] = *(const short8*)&X[(size_t)(m0 + row) * CIN + kc + col];
            *(short8*)&Bt[row][col] = *(const short8*)&W[(size_t)(n0 + row) * CIN + kc + col];
        }
        __syncthreads();
        for (int ks = 0; ks < 2; ++ks) {
            short8 a0 = *(const short8*)&At[wm * 32 + l16][ks * 32 + quad * 8];
            short8 a1 = *(const short8*)&At[wm * 32 + 16 + l16][ks * 32 + quad * 8];
            short8 b0 = *(const short8*)&Bt[wn * 32 + l16][ks * 32 + quad * 8];
            short8 b1 = *(const short8*)&Bt[wn * 32 + 16 + l16][ks * 32 + quad * 8];
            acc[0][0] = __builtin_amdgcn_mfma_f32_16x16x32_bf16(a0, b0, acc[0][0], 0, 0, 0);
            acc[0][1] = __builtin_amdgcn_mfma_f32_16x16x32_bf16(a0, b1, acc[0][1], 0, 0, 0);
            acc[1][0] = __builtin_amdgcn_mfma_f32_16x16x32_bf16(a1, b0, acc[1][0], 0, 0, 0);
            acc[1][1] = __builtin_amdgcn_mfma_f32_16x16x32_bf16(a1, b1, acc[1][1], 0, 0, 0);
        }
        __syncthreads();
    }

    if (mode == 2) {
        for (int a = 0; a < 2; ++a) for (int c = 0; c < 2; ++c)
            for (int r = 0; r < 4; ++r) {
                int ml = wm * 32 + a * 16 + quad * 4 + r;     // s-local
                int nl = wn * 32 + c * 16 + l16;              // c-local
                At[nl][ml] = tob(acc[a][c][r]);
            }
        __syncthreads();
        int bi = m0 >> 11, h = n0 >> 6, s0 = m0 & 2047;
        int crow = tid >> 2, seg = tid & 3;
        unsigned short* dp = Vd + (((size_t)(bi * HH + h) * CC) + crow) * SS + s0 + seg * 16;
        *(short8*)dp       = *(const short8*)&At[crow][seg * 16];
        *(short8*)(dp + 8) = *(const short8*)&At[crow][seg * 16 + 8];
        return;
    }

    for (int a = 0; a < 2; ++a) for (int c = 0; c < 2; ++c)
        for (int r = 0; r < 4; ++r) {
            int gm = m0 + wm * 32 + a * 16 + quad * 4 + r;
            int gn = n0 + wn * 32 + c * 16 + l16;
            float v = acc[a][c][r];
            if (mode <= 1) {
                int bi = gm >> 11, s = gm & 2047, h = gn >> 6, cc = gn & 63;
                unsigned short* d = (mode == 0) ? Qd : Kd;
                d[(((size_t)(bi * HH + h) * SS) + s) * CC + cc] = tob(v);
            } else {
                float g = 1.0f / (1.0f + __expf(-(v + bg[gn])));
                Gd[(size_t)gm * DDIM + gn] = tob(g);
            }
        }
}

// -------------------------------------------------------------- attention ---
// Split-K flash attention, fixed-shift softmax (linear in k-chunks, log2 domain):
//   partial[split] = sum_k 2^(qk*log2e + bias*log2e - SHIFT2) v
// The -SHIFT2 is folded into the MFMA accumulator init; bias*log2e is one fma
// in the exp2 argument.
// Block = 64 q rows (4 waves x 16), kdomain = 1024 keys (16 chunks),
// grid (32, 16, 2) = 1024 blocks = 4/CU.
// CHUNK-PHASE STAGGER: chunk order is rotated per block so concurrently
// resident blocks read DIFFERENT bias column windows at any instant.
// (bias rows are 8KB apart, planes 16MB apart — without stagger all blocks
// hit the same low-address-bit window in lockstep -> HBM channel
// serialization, BW pinned at ~1.1 TB/s. Softmax here is linear in chunks,
// so any processing order is exact.)
__global__ __launch_bounds__(256) void attn_kernel(
    const unsigned short* __restrict__ Q,
    const unsigned short* __restrict__ K,
    const unsigned short* __restrict__ V,
    const float* __restrict__ bias,
    float* __restrict__ part,      // [KSPLIT][MM][DDIM] fp32
    float* __restrict__ Ls)        // [KSPLIT][MM][HH]   fp32
{
    __shared__ __align__(16) unsigned short Kt[64][72];   // [key][c]
    __shared__ __align__(16) unsigned short Vt[64][72];   // [c][key]
    __shared__ __align__(16) unsigned short Pt[4][16][72];// per-wave P scratch

    int qb = blockIdx.x * 64;
    int bh = blockIdx.y;               // b*H + h
    int split = blockIdx.z;
    int ksbase = split * KDOM;
    int b = bh >> 3, h = bh & 7;
    int tid = threadIdx.x;
    int w = tid >> 6, lane = tid & 63;
    int quad = lane >> 4, l16 = lane & 15;

    // per-block chunk-phase rotation (uniform across 16 phases)
    int phase = (blockIdx.x + blockIdx.y + 8 * blockIdx.z) & (NCHUNK - 1);

    const unsigned short* Qbh = Q + (size_t)bh * SS * CC;
    const unsigned short* Kbh = K + (size_t)bh * SS * CC + (size_t)ksbase * CC;
    const unsigned short* Vbh = V + (size_t)bh * CC * SS + ksbase;
    // bias row base for this thread's r=0 row; r advances by SS floats.
    const float* brow0 = bias + (size_t)bh * SS * SS
                       + (size_t)(qb + w * 16 + quad * 4) * SS + ksbase + l16;

    int qrow = qb + w * 16 + l16;
    short8 aq0 = *(const short8*)&Qbh[(size_t)qrow * CC + quad * 8];
    short8 aq1 = *(const short8*)&Qbh[(size_t)qrow * CC + 32 + quad * 8];

    float lsum[4] = {0.f, 0.f, 0.f, 0.f};
    float4v accO[4];
    for (int jn = 0; jn < 4; ++jn) accO[jn] = (float4v)0.0f;

    // staging address components (per thread, two 16B pieces each for K and V)
    int srow0 = (tid * 8) >> 6,        scol0 = (tid * 8) & 63;
    int srow1 = (2048 + tid * 8) >> 6, scol1 = (2048 + tid * 8) & 63;

    // ---- prologue: prefetch chunk `phase` (the block's first chunk)
    short8 pk[2][2], pv[2][2];
    float  bb[2][4][4];
    {
        int kb0 = phase * 64;
        pk[0][0] = *(const short8*)&Kbh[(size_t)(kb0 + srow0) * CC + scol0];
        pk[0][1] = *(const short8*)&Kbh[(size_t)(kb0 + srow1) * CC + scol1];
        pv[0][0] = *(const short8*)&Vbh[(size_t)srow0 * SS + kb0 + scol0];
        pv[0][1] = *(const short8*)&Vbh[(size_t)srow1 * SS + kb0 + scol1];
#pragma unroll
        for (int j = 0; j < 4; ++j)
#pragma unroll
            for (int r = 0; r < 4; ++r)
                bb[0][j][r] = brow0[r * SS + kb0 + j * 16];
    }

#pragma unroll
    for (int c = 0; c < NCHUNK; ++c) {
        __syncthreads();   // previous chunk's Kt/Vt fully consumed
        *(short8*)&Kt[srow0][scol0] = pk[c & 1][0];
        *(short8*)&Kt[srow1][scol1] = pk[c & 1][1];
        *(short8*)&Vt[srow0][scol0] = pv[c & 1][0];
        *(short8*)&Vt[srow1][scol1] = pv[c & 1][1];

        // issue next chunk's loads (latency hidden behind this chunk's work)
        if (c + 1 < NCHUNK) {
            int kbn = ((c + 1 + phase) & (NCHUNK - 1)) * 64;
            pk[(c + 1) & 1][0] = *(const short8*)&Kbh[(size_t)(kbn + srow0) * CC + scol0];
            pk[(c + 1) & 1][1] = *(const short8*)&Kbh[(size_t)(kbn + srow1) * CC + scol1];
            pv[(c + 1) & 1][0] = *(const short8*)&Vbh[(size_t)srow0 * SS + kbn + scol0];
            pv[(c + 1) & 1][1] = *(const short8*)&Vbh[(size_t)srow1 * SS + kbn + scol1];
#pragma unroll
            for (int j = 0; j < 4; ++j)
#pragma unroll
                for (int r = 0; r < 4; ++r)
                    bb[(c + 1) & 1][j][r] = brow0[r * SS + kbn + j * 16];
        }

        __syncthreads();

        float4v sa[4];
#pragma unroll
        for (int j = 0; j < 4; ++j) sa[j] = (float4v)(-SHIFT2);  // fold shift into acc init
#pragma unroll
        for (int j = 0; j < 4; ++j) {
            short8 bk0 = *(const short8*)&Kt[j * 16 + l16][quad * 8];
            short8 bk1 = *(const short8*)&Kt[j * 16 + l16][32 + quad * 8];
            sa[j] = __builtin_amdgcn_mfma_f32_16x16x32_bf16(aq0, bk0, sa[j], 0, 0, 0);
            sa[j] = __builtin_amdgcn_mfma_f32_16x16x32_bf16(aq1, bk1, sa[j], 0, 0, 0);
        }

#pragma unroll
        for (int j = 0; j < 4; ++j)
#pragma unroll
            for (int r = 0; r < 4; ++r) {
                float p = __builtin_amdgcn_exp2f(fmaf(bb[c & 1][j][r], LOG2E, sa[j][r]));
                lsum[r] += p;
                Pt[w][quad * 4 + r][j * 16 + l16] = tob(p);
            }

#pragma unroll
        for (int ks = 0; ks < 2; ++ks) {
            short8 ap = *(const short8*)&Pt[w][l16][ks * 32 + quad * 8];
#pragma unroll
            for (int jn = 0; jn < 4; ++jn) {
                short8 bv = *(const short8*)&Vt[jn * 16 + l16][ks * 32 + quad * 8];
                accO[jn] = __builtin_amdgcn_mfma_f32_16x16x32_bf16(ap, bv, accO[jn], 0, 0, 0);
            }
        }
    }

    // row-sum reduce across 16 l16 lanes
    for (int r = 0; r < 4; ++r) {
        float s = lsum[r];
        s += __shfl_xor(s, 1, 64);
        s += __shfl_xor(s, 2, 64);
        s += __shfl_xor(s, 4, 64);
        s += __shfl_xor(s, 8, 64);
        lsum[r] = s;
    }

    // epilogue: raw partials (division + gating deferred to combine kernel)
    int mrow = b * SS + qb + w * 16 + quad * 4;          // +r
    float* pOut = part + (size_t)split * MM * DDIM;
    for (int jn = 0; jn < 4; ++jn)
        for (int r = 0; r < 4; ++r)
            pOut[(size_t)(mrow + r) * DDIM + h * 64 + jn * 16 + l16] = accO[jn][r];
    if (l16 == 0)
        for (int r = 0; r < 4; ++r)
            Ls[((size_t)split * MM + mrow + r) * HH + h] = lsum[r];
}

// ----------------------------------------------------------------- combine --
// Og = (sum_s part_s) / (sum_s Ls_s) * G  -> bf16 [MM][DDIM]
__global__ __launch_bounds__(256) void combine_kernel(
    const float* __restrict__ part,
    const float* __restrict__ Ls,
    const unsigned short* __restrict__ G,
    unsigned short* __restrict__ Og)
{
    int i = blockIdx.x * 256 + threadIdx.x;   // 0 .. MM*DDIM/4-1
    int row = i >> 7;
    int c4  = (i & 127) << 2;
    int h   = c4 >> 6;
    float l = 0.f;
#pragma unroll
    for (int s = 0; s < KSPLIT; ++s)
        l += Ls[((size_t)s * MM + row) * HH + h];
    float rl = 1.0f / l;
    float ax = 0.f, ay = 0.f, az = 0.f, aw = 0.f;
#pragma unroll
    for (int s = 0; s < KSPLIT; ++s) {
        float4 t = *(const float4*)(part + (size_t)s * MM * DDIM + (size_t)row * DDIM + c4);
        ax += t.x; ay += t.y; az += t.z; aw += t.w;
    }
    ushort4 g = *(const ushort4*)&G[(size_t)row * DDIM + c4];
    ushort4 o;
    o.x = tob(ax * rl * fromb(g.x));
    o.y = tob(ay * rl * fromb(g.y));
    o.z = tob(az * rl * fromb(g.z));
    o.w = tob(aw * rl * fromb(g.w));
    *(ushort4*)&Og[(size_t)row * DDIM + c4] = o;
}

// ---------------------------------------------------------- output GEMM -----
__global__ __launch_bounds__(256) void out_gemm(
    const unsigned short* __restrict__ Og,
    const unsigned short* __restrict__ W,
    const float* __restrict__ bo,
    float* __restrict__ out)
{
    __shared__ __align__(16) unsigned short At[64][72];
    __shared__ __align__(16) unsigned short Bt[64][72];

    int m0 = blockIdx.y * 64;
    int n0 = blockIdx.x * 64;
    int tid = threadIdx.x;
    int w = tid >> 6, lane = tid & 63;
    int quad = lane >> 4, l16 = lane & 15;
    int wm = w & 1, wn = w >> 1;

    float4v acc[2][2];
    for (int a = 0; a < 2; ++a) for (int c = 0; c < 2; ++c) acc[a][c] = (float4v)0.0f;

    for (int kc = 0; kc < DDIM; kc += 64) {
        for (int it = 0; it < 2; ++it) {
            int idx = it * 2048 + tid * 8;
            int row = idx >> 6, col = idx & 63;
            *(short8*)&At[row][col] = *(const short8*)&Og[(size_t)(m0 + row) * DDIM + kc + col];
            *(short8*)&Bt[row][col] = *(const short8*)&W[(size_t)(n0 + row) * DDIM + kc + col];
        }
        __syncthreads();
        for (int ks = 0; ks < 2; ++ks) {
            short8 a0 = *(const short8*)&At[wm * 32 + l16][ks * 32 + quad * 8];
            short8 a1 = *(const short8*)&At[wm * 32 + 16 + l16][ks * 32 + quad * 8];
            short8 b0 = *(const short8*)&Bt[wn * 32 + l16][ks * 32 + quad * 8];
            short8 b1 = *(const short8*)&Bt[wn * 32 + 16 + l16][ks * 32 + quad * 8];
            acc[0][0] = __builtin_amdgcn_mfma_f32_16x16x32_bf16(a0, b0, acc[0][0], 0, 0, 0);
            acc[0][1] = __builtin_amdgcn_mfma_f32_16x16x32_bf16(a0, b1, acc[0][1], 0, 0, 0);
            acc[1][0] = __builtin_amdgcn_mfma_f32_16x16x32_bf16(a1, b0, acc[1][0], 0, 0, 0);
            acc[1][1] = __builtin_amdgcn_mfma_f32_16x16x32_bf16(a1, b1, acc[1][1], 0, 0, 0);
        }
        __syncthreads();
    }

    for (int a = 0; a < 2; ++a) for (int c = 0; c < 2; ++c)
        for (int r = 0; r < 4; ++r) {
            int gm = m0 + wm * 32 + a * 16 + quad * 4 + r;
            int gn = n0 + wn * 32 + c * 16 + l16;
            out[(size_t)gm * DDIM + gn] = acc[a][c][r] + bo[gn];
        }
}

// ------------------------------------------------------------------ launch --
extern "C" void kernel_launch(void* const* d_in, const int* in_sizes, int n_in,
                              void* d_out, int out_size, void* d_ws, size_t ws_size,
                              hipStream_t stream)
{
    const float* x    = (const float*)d_in[0];
    const float* bias = (const float*)d_in[1];
    const float* Wq   = (const float*)d_in[2];
    const float* Wk   = (const float*)d_in[3];
    const float* Wv   = (const float*)d_in[4];
    const float* Wo   = (const float*)d_in[5];
    const float* bo   = (const float*)d_in[6];
    const float* Wg   = (const float*)d_in[7];
    const float* bg   = (const float*)d_in[8];
    float* out = (float*)d_out;

    char* ws = (char*)d_ws;
    auto alloc = [&](size_t bytes) { char* p = ws; ws += (bytes + 255) & ~(size_t)255; return p; };
    unsigned short* xb  = (unsigned short*)alloc((size_t)MM * CIN * 2);
    unsigned short* wqb = (unsigned short*)alloc((size_t)DDIM * CIN * 2);
    unsigned short* wkb = (unsigned short*)alloc((size_t)DDIM * CIN * 2);
    unsigned short* wvb = (unsigned short*)alloc((size_t)DDIM * CIN * 2);
    unsigned short* wgb = (unsigned short*)alloc((size_t)DDIM * CIN * 2);
    unsigned short* wob = (unsigned short*)alloc((size_t)DDIM * CIN * 2);
    unsigned short* Qh  = (unsigned short*)alloc((size_t)BB * HH * SS * CC * 2);
    unsigned short* Kh  = (unsigned short*)alloc((size_t)BB * HH * SS * CC * 2);
    unsigned short* Vh  = (unsigned short*)alloc((size_t)BB * HH * SS * CC * 2);
    unsigned short* Gt  = (unsigned short*)alloc((size_t)MM * DDIM * 2);
    unsigned short* Om  = (unsigned short*)alloc((size_t)MM * DDIM * 2);
    float* part = (float*)alloc((size_t)KSPLIT * MM * DDIM * 4);   // 16.8 MB
    float* Lsum = (float*)alloc((size_t)KSPLIT * MM * HH * 4);     // 256 KB

    convert_all<<<3328, 256, 0, stream>>>(x, Wq, Wk, Wv, Wg, Wo,
                                          xb, wqb, wkb, wvb, wgb, wob);
    proj_gemm<<<dim3(DDIM / 64, MM / 64, 4), 256, 0, stream>>>(
        xb, wqb, wkb, wvb, wgb, bg, Qh, Kh, Vh, Gt);
    attn_kernel<<<dim3(SS / 64, BB * HH, KSPLIT), 256, 0, stream>>>(
        Qh, Kh, Vh, bias, part, Lsum);
    combine_kernel<<<(MM * DDIM / 4) / 256, 256, 0, stream>>>(part, Lsum, Gt, Om);
    out_gemm<<<dim3(DDIM / 64, MM / 64), 256, 0, stream>>>(Om, wob, bo, out);
}